// Round 13
// baseline (254.299 us; speedup 1.0000x reference)
//
#include <hip/hip_runtime.h>
#include <hip/hip_bf16.h>
#include <math.h>

#define NN    65536
#define EE    524288
#define BBG   64
#define PERG  1024
#define KKEEP 820
#define FF    128
#define EPSBN 1e-5f
#define CHUNK 41
#define NCH   20

typedef __attribute__((ext_vector_type(8))) short bf16x8;
typedef __attribute__((ext_vector_type(4))) float f32x4;
typedef unsigned short ushort_t;
typedef unsigned int uint_t;

// ---------------- degree histogram ----------------
__global__ __launch_bounds__(256) void k_deg(const int* __restrict__ ei,
                                             int* __restrict__ deg) {
    int e = blockIdx.x * 256 + threadIdx.x;
    if (e < EE) atomicAdd(&deg[ei[EE + e]], 1);
}

// ---------------- 3-stage exclusive scan of deg -> starts ----------------
__global__ __launch_bounds__(256) void k_scan1(const int* __restrict__ deg,
                                               int* __restrict__ spart,
                                               int* __restrict__ bsum) {
    int t = threadIdx.x;
    int i = blockIdx.x * 256 + t;
    __shared__ int sh[256];
    int v = deg[i];
    sh[t] = v;
    __syncthreads();
    for (int o = 1; o < 256; o <<= 1) {
        int u = (t >= o) ? sh[t - o] : 0;
        __syncthreads();
        sh[t] += u;
        __syncthreads();
    }
    spart[i] = sh[t];
    if (t == 255) bsum[blockIdx.x] = sh[255];
}

__global__ __launch_bounds__(256) void k_scan2(const int* __restrict__ bsum,
                                               int* __restrict__ boff) {
    int t = threadIdx.x;
    __shared__ int sh[256];
    int v = bsum[t];
    sh[t] = v;
    __syncthreads();
    for (int o = 1; o < 256; o <<= 1) {
        int u = (t >= o) ? sh[t - o] : 0;
        __syncthreads();
        sh[t] += u;
        __syncthreads();
    }
    boff[t] = sh[t] - v;
}

__global__ __launch_bounds__(256) void k_scan3(const int* __restrict__ deg,
                                               const int* __restrict__ spart,
                                               const int* __restrict__ boff,
                                               int* __restrict__ starts,
                                               int* __restrict__ cursor) {
    int i = blockIdx.x * 256 + threadIdx.x;
    int st = spart[i] - deg[i] + boff[i >> 8];
    starts[i] = st;
    cursor[i] = st;
    if (i == 0) starts[NN] = EE;
}

// ---------------- scatter edges into CSR ----------------
__global__ __launch_bounds__(256) void k_scatter(const int* __restrict__ ei,
                                                 int* __restrict__ cursor,
                                                 int* __restrict__ ssrc) {
    int e = blockIdx.x * 256 + threadIdx.x;
    if (e >= EE) return;
    int s = ei[e];
    int d = ei[EE + e];
    int pos = atomicAdd(&cursor[d], 1);
    ssrc[pos] = s;
}

// ---------------- per-node neighbor-list sort: make ssrc deterministic ----------------
__global__ __launch_bounds__(256) void k_sortnb(const int* __restrict__ starts,
                                                int* __restrict__ ssrc) {
    int n = blockIdx.x * 256 + threadIdx.x;
    if (n >= NN) return;
    int d0 = starts[n], d1 = starts[n + 1];
    for (int i = d0 + 1; i < d1; ++i) {
        int key = ssrc[i];
        int j = i - 1;
        while (j >= d0 && ssrc[j] > key) {
            ssrc[j + 1] = ssrc[j];
            --j;
        }
        ssrc[j + 1] = key;
    }
}

// ---------------- split W = [Wl||Wr] into bf16 hi/lo, cell-major layout ----------------
// Bcell cell (c, idx): idx<128 -> hi of output idx, idx>=128 -> lo of output idx-128,
// covering k = c*8 .. c*8+7. Frag read for 16 lanes = 256B contiguous.
__global__ __launch_bounds__(256) void k_wcvt(const float* __restrict__ Wl,
                                              const float* __restrict__ Wr,
                                              ushort_t* __restrict__ Bcell) {
    int i = blockIdx.x * 256 + threadIdx.x;   // 0..32767
    int o = i >> 8, k = i & 255;
    float v = (k < 128) ? Wl[o * FF + k] : Wr[o * FF + k - 128];
    uint_t u = __float_as_uint(v);
    float hif = __uint_as_float(u & 0xffff0000u);
    float lof = v - hif;
    int c = k >> 3, j = k & 7;
    Bcell[((size_t)(c * 256 + o)) * 8 + j]       = (ushort_t)(u >> 16);
    Bcell[((size_t)(c * 256 + 128 + o)) * 8 + j] = (ushort_t)(__float_as_uint(lof) >> 16);
}

// ---------------- fused gather + GEMM: h = [mean||x] @ [Wl||Wr]^T + bl ----------------
// 512 blocks x 128 rows, 512 thr (8 waves x 16 rows). LDS holds the f32 A-tile
// in cell-major [c 0..31][row 0..127][8]: c<16 = gathered mean, c>=16 = x.
// B read from global cell-major (128KB, L2-resident, coalesced 256B frags).
__global__ __launch_bounds__(512, 1) void k_gemm_fused(const float* __restrict__ x,
                                                       const int* __restrict__ ssrc,
                                                       const int* __restrict__ starts,
                                                       const ushort_t* __restrict__ Bcell,
                                                       const float* __restrict__ blv,
                                                       float* __restrict__ h,
                                                       float* __restrict__ pstats) {
    __shared__ __align__(16) float Ac[32 * 128 * 8];   // 128 KB
    __shared__ float ls1[8][128], ls2[8][128];         // 8 KB
    const int tid  = threadIdx.x;
    const int w    = tid >> 6;
    const int lane = tid & 63;
    const int half = lane >> 5;
    const int l32  = lane & 31;
    const int r0   = blockIdx.x * 128;
    const int rw   = w * 16;                 // wave's row base within tile

    // ---- P1: stage x rows -> cells 16..31 (2 rows per pass, coalesced) ----
#pragma unroll
    for (int q = 0; q < 16; q += 2) {
        int rloc = rw + q + half;
        f32x4 v = *(const f32x4*)(x + (size_t)(r0 + rloc) * FF + l32 * 4);
        int c = 16 + (l32 >> 1);
        *(f32x4*)&Ac[(c * 128 + rloc) * 8 + (l32 & 1) * 4] = v;
    }

    // ---- P2: gather mean per row -> cells 0..15 (bit-identical to r11 order) ----
    for (int q = 0; q < 16; ++q) {
        int rloc = rw + q;
        int n = r0 + rloc;
        int d0 = starts[n], d1 = starts[n + 1];
        f32x4 a0 = (f32x4){0.f, 0.f, 0.f, 0.f};
        f32x4 a1 = (f32x4){0.f, 0.f, 0.f, 0.f};
        f32x4 a2 = (f32x4){0.f, 0.f, 0.f, 0.f};
        f32x4 a3 = (f32x4){0.f, 0.f, 0.f, 0.f};
        int e = d0 + half;
        for (; e + 6 < d1; e += 8) {
            int s0 = ssrc[e];
            int s1 = ssrc[e + 2];
            int s2 = ssrc[e + 4];
            int s3 = ssrc[e + 6];
            a0 += *(const f32x4*)(x + (size_t)s0 * FF + l32 * 4);
            a1 += *(const f32x4*)(x + (size_t)s1 * FF + l32 * 4);
            a2 += *(const f32x4*)(x + (size_t)s2 * FF + l32 * 4);
            a3 += *(const f32x4*)(x + (size_t)s3 * FF + l32 * 4);
        }
        if (e < d1) {
            a0 += *(const f32x4*)(x + (size_t)ssrc[e] * FF + l32 * 4);
            e += 2;
        }
        if (e < d1) {
            a1 += *(const f32x4*)(x + (size_t)ssrc[e] * FF + l32 * 4);
            e += 2;
        }
        if (e < d1) {
            a2 += *(const f32x4*)(x + (size_t)ssrc[e] * FF + l32 * 4);
        }
        f32x4 acc = (a0 + a1) + (a2 + a3);
        f32x4 oth;
#pragma unroll
        for (int j = 0; j < 4; ++j) oth[j] = __shfl_xor(acc[j], 32);
        acc += oth;
        if (half == 0) {
            float inv = 1.0f / fmaxf((float)(d1 - d0), 1.0f);
            acc *= inv;
            int c = l32 >> 1;
            *(f32x4*)&Ac[(c * 128 + rloc) * 8 + (l32 & 1) * 4] = acc;
        }
    }
    __syncthreads();

    // ---- P3: MFMA over K=256 (A from LDS, split to bf16 hi/lo; B from L2) ----
    const int bcol   = lane & 15;
    const int arow_l = rw + (lane & 15);

    f32x4 acc[8];
#pragma unroll
    for (int n = 0; n < 8; ++n) acc[n] = (f32x4){0.f, 0.f, 0.f, 0.f};

#pragma unroll
    for (int ks = 0; ks < 8; ++ks) {
        const int c = ks * 4 + (lane >> 4);
        const float* ap = &Ac[(c * 128 + arow_l) * 8];
        f32x4 A0 = *(const f32x4*)ap;
        f32x4 A1 = *(const f32x4*)(ap + 4);
        bf16x8 ah, al;
#pragma unroll
        for (int e = 0; e < 8; ++e) {
            float v = (e < 4) ? A0[e] : A1[e - 4];
            uint_t u = __float_as_uint(v);
            float hif = __uint_as_float(u & 0xffff0000u);
            float lof = v - hif;
            ah[e] = (short)(u >> 16);
            al[e] = (short)(__float_as_uint(lof) >> 16);
        }
        const int cbase = c * 256;
        bf16x8 bh[8], bl8[8];
#pragma unroll
        for (int n = 0; n < 8; ++n) {
            int oo = n * 16 + bcol;
            bh[n]  = *(const bf16x8*)&Bcell[((size_t)(cbase + oo)) * 8];
            bl8[n] = *(const bf16x8*)&Bcell[((size_t)(cbase + 128 + oo)) * 8];
        }
#pragma unroll
        for (int n = 0; n < 8; ++n) {
            acc[n] = __builtin_amdgcn_mfma_f32_16x16x32_bf16(ah, bh[n],  acc[n], 0, 0, 0);
            acc[n] = __builtin_amdgcn_mfma_f32_16x16x32_bf16(ah, bl8[n], acc[n], 0, 0, 0);
            acc[n] = __builtin_amdgcn_mfma_f32_16x16x32_bf16(al, bh[n],  acc[n], 0, 0, 0);
        }
    }

    // ---- epilogue: +bias, store h, per-block BN partials (no atomics) ----
    const int orow = r0 + rw + (lane >> 4) * 4;
#pragma unroll
    for (int n = 0; n < 8; ++n) {
        int col = n * 16 + bcol;
        float b = blv[col];
        float p1 = 0.f, p2 = 0.f;
#pragma unroll
        for (int j = 0; j < 4; ++j) {
            float v = acc[n][j] + b;
            h[(size_t)(orow + j) * FF + col] = v;
            p1 += v;
            p2 += v * v;
        }
        p1 += __shfl_xor(p1, 16); p1 += __shfl_xor(p1, 32);
        p2 += __shfl_xor(p2, 16); p2 += __shfl_xor(p2, 32);
        if (lane < 16) { ls1[w][col] = p1; ls2[w][col] = p2; }
    }
    __syncthreads();
    if (tid < 128) {
        float a = 0.f, b2 = 0.f;
#pragma unroll
        for (int ww = 0; ww < 8; ++ww) {
            a  += ls1[ww][tid];
            b2 += ls2[ww][tid];
        }
        pstats[(size_t)blockIdx.x * 256 + tid]       = a;
        pstats[(size_t)blockIdx.x * 256 + 128 + tid] = b2;
    }
}

// ---------------- deterministic 2-stage stats reduction (512 partials) ----------------
__global__ __launch_bounds__(256) void k_red1(const float* __restrict__ pstats,
                                              float* __restrict__ pr) {
    int t = threadIdx.x;
    int r = blockIdx.x;             // 0..31
    float s = 0.f;
    for (int i = 0; i < 16; ++i)
        s += pstats[(size_t)(r * 16 + i) * 256 + t];
    pr[r * 256 + t] = s;
}

__global__ __launch_bounds__(256) void k_red2(const float* __restrict__ pr,
                                              float* __restrict__ stats) {
    int t = threadIdx.x;
    float s = 0.f;
    for (int r = 0; r < 32; ++r)
        s += pr[r * 256 + t];
    stats[t] = s;
}

// ---------------- score (BN params inline) ----------------
__global__ __launch_bounds__(256) void k_score(const float* __restrict__ h,
                                               const float* __restrict__ stats,
                                               const float* __restrict__ gamma,
                                               const float* __restrict__ beta,
                                               const float* __restrict__ attn,
                                               float* __restrict__ score) {
    int tid = threadIdx.x;
    int l32 = tid & 31;
    int n   = blockIdx.x * 8 + (tid >> 5);
    int f0  = l32 * 4;
    float4 su = *(const float4*)&stats[f0];
    float4 sq = *(const float4*)&stats[128 + f0];
    float4 g4 = *(const float4*)&gamma[f0];
    float4 b4 = *(const float4*)&beta[f0];
    float4 a4 = *(const float4*)&attn[f0];
    float an = a4.x * a4.x + a4.y * a4.y + a4.z * a4.z + a4.w * a4.w;
#pragma unroll
    for (int off = 16; off > 0; off >>= 1) an += __shfl_xor(an, off);
    float inva = 1.0f / sqrtf(an);
    float invN = 1.0f / (float)NN;
    float m0 = su.x * invN, m1 = su.y * invN, m2 = su.z * invN, m3 = su.w * invN;
    float sc0 = g4.x / sqrtf(sq.x * invN - m0 * m0 + EPSBN);
    float sc1 = g4.y / sqrtf(sq.y * invN - m1 * m1 + EPSBN);
    float sc2 = g4.z / sqrtf(sq.z * invN - m2 * m2 + EPSBN);
    float sc3 = g4.w / sqrtf(sq.w * invN - m3 * m3 + EPSBN);
    float4 hv = *(const float4*)&h[(size_t)n * FF + f0];
    float v0 = fmaxf((hv.x - m0) * sc0 + b4.x, 0.f);
    float v1 = fmaxf((hv.y - m1) * sc1 + b4.y, 0.f);
    float v2 = fmaxf((hv.z - m2) * sc2 + b4.z, 0.f);
    float v3 = fmaxf((hv.w - m3) * sc3 + b4.w, 0.f);
    float s = (v0 * a4.x + v1 * a4.y + v2 * a4.z + v3 * a4.w) * inva;
#pragma unroll
    for (int off = 16; off > 0; off >>= 1) s += __shfl_xor(s, off);
    if (l32 == 0) score[n] = s;
}

// ---------------- per-graph bitonic sort (desc, stable) + perm/node_map ----------------
__global__ __launch_bounds__(1024) void k_topk(const float* __restrict__ score,
                                               int* __restrict__ nmap,
                                               int* __restrict__ plist,
                                               float* __restrict__ out_batch) {
    __shared__ unsigned long long keys[PERG];
    int b = blockIdx.x;
    int t = threadIdx.x;
    float s = score[b * PERG + t];
    unsigned u = __float_as_uint(s);
    u = (u & 0x80000000u) ? ~u : (u | 0x80000000u);
    keys[t] = ((unsigned long long)u << 10) | (unsigned long long)(1023 - t);
    __syncthreads();
    for (int k = 2; k <= PERG; k <<= 1) {
        for (int j = k >> 1; j > 0; j >>= 1) {
            int l = t ^ j;
            if (l > t) {
                bool asc = ((t & k) != 0);
                unsigned long long a = keys[t], c = keys[l];
                if ((a > c) == asc) { keys[t] = c; keys[l] = a; }
            }
            __syncthreads();
        }
    }
    if (t < KKEEP) {
        int idx = 1023 - (int)(keys[t] & 1023ull);
        int g   = b * PERG + idx;
        int nid = b * KKEEP + t;
        plist[nid]     = g;
        nmap[g]        = nid;
        out_batch[nid] = (float)b;
    }
}

// ---------------- hp = BNrelu(h[perm]) * tanh(score[perm]) + fused pool partials ----
__global__ __launch_bounds__(256) void k_hp2(const float* __restrict__ h,
                                             const float* __restrict__ score,
                                             const int* __restrict__ plist,
                                             const float* __restrict__ stats,
                                             const float* __restrict__ gamma,
                                             const float* __restrict__ beta,
                                             float* __restrict__ out_hp,
                                             float* __restrict__ pflat) {
    int b   = blockIdx.x;             // 0..1279
    int g   = b / NCH, c = b % NCH;
    int tid = threadIdx.x;
    int f   = tid & 127, half = tid >> 7;
    int r0  = g * KKEEP + c * CHUNK;

    __shared__ float tts[CHUNK];
    __shared__ int   gl[CHUNK];
    if (tid < CHUNK) {
        int gg = plist[r0 + tid];
        gl[tid]  = gg;
        tts[tid] = tanhf(score[gg]);
    }
    __syncthreads();

    float invN = 1.0f / (float)NN;
    float m  = stats[f] * invN;
    float sc = gamma[f] / sqrtf(stats[128 + f] * invN - m * m + EPSBN);
    float bb = beta[f];
    float s = 0.f, mx = -INFINITY;
    for (int i = half; i < CHUNK; i += 2) {
        int gg = gl[i];
        float v = fmaxf((h[(size_t)gg * FF + f] - m) * sc + bb, 0.f) * tts[i];
        out_hp[(size_t)(r0 + i) * FF + f] = v;
        s += v;
        mx = fmaxf(mx, v);
    }
    __shared__ float ls[256], lm[256];
    ls[tid] = s;
    lm[tid] = mx;
    __syncthreads();
    if (half == 0) {
        pflat[(size_t)b * 256 + f]       = ls[f] + ls[128 + f];
        pflat[(size_t)b * 256 + 128 + f] = fmaxf(lm[f], lm[128 + f]);
    }
}

// ---------------- final per-graph combine (fixed order) ----------------
__global__ __launch_bounds__(256) void k_flat2(const float* __restrict__ pflat,
                                               float* __restrict__ out_flat) {
    int b = blockIdx.x;
    int t = threadIdx.x;
    if (t < 128) {
        float s = 0.f;
        for (int c = 0; c < NCH; ++c)
            s += pflat[(size_t)(b * NCH + c) * 256 + t];
        out_flat[b * 256 + t] = s;
    } else {
        int f = t - 128;
        float m = -INFINITY;
        for (int c = 0; c < NCH; ++c)
            m = fmaxf(m, pflat[(size_t)(b * NCH + c) * 256 + 128 + f]);
        out_flat[b * 256 + 128 + f] = m;
    }
}

// ---------------- edge reindex ----------------
__global__ __launch_bounds__(256) void k_edge(const int* __restrict__ ei,
                                              const int* __restrict__ nmap,
                                              float* __restrict__ out_edge) {
    int e = blockIdx.x * 256 + threadIdx.x;
    if (e >= EE) return;
    int s  = ei[e];
    int d  = ei[EE + e];
    int ns = nmap[s];
    int nd = nmap[d];
    bool keep = (ns >= 0) && (nd >= 0);
    out_edge[e]      = keep ? (float)ns : -1.0f;
    out_edge[EE + e] = keep ? (float)nd : -1.0f;
}

extern "C" void kernel_launch(void* const* d_in, const int* in_sizes, int n_in,
                              void* d_out, int out_size, void* d_ws, size_t ws_size,
                              hipStream_t stream) {
    const float* x    = (const float*)d_in[0];
    const int*   ei   = (const int*)d_in[1];
    const float* Wl   = (const float*)d_in[3];
    const float* bl   = (const float*)d_in[4];
    const float* Wr   = (const float*)d_in[5];
    const float* gam  = (const float*)d_in[6];
    const float* bet  = (const float*)d_in[7];
    const float* attn = (const float*)d_in[8];

    // workspace layout
    float*    pstats = (float*)d_ws;                   // 512*256
    float*    pr     = pstats + 512 * 256;             // 32*256
    float*    pflat  = pr + 32 * 256;                  // 1280*256
    float*    stats  = pflat + 1280 * 256;             // 256
    ushort_t* Bcell  = (ushort_t*)(stats + 256);       // 32*256*8 ushorts (128 KB)
    float*    score  = (float*)(Bcell + 32 * 256 * 8); // NN   (aliased: deg)
    int*      nmap   = (int*)(score + NN);             // NN   (aliased: spart)
    int*      plist  = nmap + NN;                      // BBG*KKEEP
    int*      starts = plist + BBG * KKEEP;            // NN+1
    int*      cursor = starts + NN + 1;                // NN
    int*      ssrc   = cursor + NN;                    // EE
    int*      bsum   = ssrc + EE;                      // 256
    int*      boff   = bsum + 256;                     // 256
    float*    h      = (float*)(boff + 256);           // NN*FF

    int* deg   = (int*)score;   // dead before k_score writes score
    int* spart = (int*)nmap;    // dead before nmap memset

    // output layout (all float32)
    float* out       = (float*)d_out;
    float* out_hp    = out;                                // 52480*128
    float* out_flat  = out_hp + (size_t)BBG * KKEEP * FF;  // 64*256
    float* out_edge  = out_flat + BBG * 256;               // 2*EE
    float* out_batch = out_edge + 2 * EE;                  // 52480

    hipMemsetAsync(deg, 0, (size_t)NN * sizeof(int), stream);

    k_wcvt<<<128, 256, 0, stream>>>(Wl, Wr, Bcell);
    k_deg<<<EE / 256, 256, 0, stream>>>(ei, deg);
    k_scan1<<<256, 256, 0, stream>>>(deg, spart, bsum);
    k_scan2<<<1, 256, 0, stream>>>(bsum, boff);
    k_scan3<<<256, 256, 0, stream>>>(deg, spart, boff, starts, cursor);
    k_scatter<<<EE / 256, 256, 0, stream>>>(ei, cursor, ssrc);
    k_sortnb<<<NN / 256, 256, 0, stream>>>(starts, ssrc);

    hipMemsetAsync(nmap, 0xFF, (size_t)NN * sizeof(int), stream);  // spart dead now

    k_gemm_fused<<<NN / 128, 512, 0, stream>>>(x, ssrc, starts, Bcell, bl, h, pstats);
    k_red1<<<32, 256, 0, stream>>>(pstats, pr);
    k_red2<<<1, 256, 0, stream>>>(pr, stats);
    k_score<<<NN / 8, 256, 0, stream>>>(h, stats, gam, bet, attn, score);
    k_topk<<<BBG, 1024, 0, stream>>>(score, nmap, plist, out_batch);
    k_hp2<<<BBG * NCH, 256, 0, stream>>>(h, score, plist, stats, gam, bet, out_hp, pflat);
    k_flat2<<<BBG, 256, 0, stream>>>(pflat, out_flat);
    k_edge<<<EE / 256, 256, 0, stream>>>(ei, nmap, out_edge);
}

// Round 14
// 212.887 us; speedup vs baseline: 1.1945x; 1.1945x over previous
//
#include <hip/hip_runtime.h>
#include <hip/hip_bf16.h>
#include <math.h>

#define NN    65536
#define EE    524288
#define BBG   64
#define PERG  1024
#define KKEEP 820
#define FF    128
#define EPSBN 1e-5f
#define CHUNK 41
#define NCH   20

typedef __attribute__((ext_vector_type(8))) short bf16x8;
typedef __attribute__((ext_vector_type(4))) float f32x4;
typedef unsigned short ushort_t;
typedef unsigned int uint_t;

// ---------------- degree histogram ----------------
__global__ __launch_bounds__(256) void k_deg(const int* __restrict__ ei,
                                             int* __restrict__ deg) {
    int e = blockIdx.x * 256 + threadIdx.x;
    if (e < EE) atomicAdd(&deg[ei[EE + e]], 1);
}

// ---------------- 3-stage exclusive scan of deg -> starts ----------------
__global__ __launch_bounds__(256) void k_scan1(const int* __restrict__ deg,
                                               int* __restrict__ spart,
                                               int* __restrict__ bsum) {
    int t = threadIdx.x;
    int i = blockIdx.x * 256 + t;
    __shared__ int sh[256];
    int v = deg[i];
    sh[t] = v;
    __syncthreads();
    for (int o = 1; o < 256; o <<= 1) {
        int u = (t >= o) ? sh[t - o] : 0;
        __syncthreads();
        sh[t] += u;
        __syncthreads();
    }
    spart[i] = sh[t];
    if (t == 255) bsum[blockIdx.x] = sh[255];
}

__global__ __launch_bounds__(256) void k_scan2(const int* __restrict__ bsum,
                                               int* __restrict__ boff) {
    int t = threadIdx.x;
    __shared__ int sh[256];
    int v = bsum[t];
    sh[t] = v;
    __syncthreads();
    for (int o = 1; o < 256; o <<= 1) {
        int u = (t >= o) ? sh[t - o] : 0;
        __syncthreads();
        sh[t] += u;
        __syncthreads();
    }
    boff[t] = sh[t] - v;
}

__global__ __launch_bounds__(256) void k_scan3(const int* __restrict__ deg,
                                               const int* __restrict__ spart,
                                               const int* __restrict__ boff,
                                               int* __restrict__ starts,
                                               int* __restrict__ cursor) {
    int i = blockIdx.x * 256 + threadIdx.x;
    int st = spart[i] - deg[i] + boff[i >> 8];
    starts[i] = st;
    cursor[i] = st;
    if (i == 0) starts[NN] = EE;
}

// ---------------- scatter edges into CSR ----------------
__global__ __launch_bounds__(256) void k_scatter(const int* __restrict__ ei,
                                                 int* __restrict__ cursor,
                                                 int* __restrict__ ssrc) {
    int e = blockIdx.x * 256 + threadIdx.x;
    if (e >= EE) return;
    int s = ei[e];
    int d = ei[EE + e];
    int pos = atomicAdd(&cursor[d], 1);
    ssrc[pos] = s;
}

// ---------------- per-node neighbor-list sort: make ssrc deterministic ----------------
__global__ __launch_bounds__(256) void k_sortnb(const int* __restrict__ starts,
                                                int* __restrict__ ssrc) {
    int n = blockIdx.x * 256 + threadIdx.x;
    if (n >= NN) return;
    int d0 = starts[n], d1 = starts[n + 1];
    for (int i = d0 + 1; i < d1; ++i) {
        int key = ssrc[i];
        int j = i - 1;
        while (j >= d0 && ssrc[j] > key) {
            ssrc[j + 1] = ssrc[j];
            --j;
        }
        ssrc[j + 1] = key;
    }
}

// ---------------- split W = [Wl||Wr] into bf16 hi/lo ----------------
__global__ __launch_bounds__(256) void k_wcvt(const float* __restrict__ Wl,
                                              const float* __restrict__ Wr,
                                              ushort_t* __restrict__ Whi,
                                              ushort_t* __restrict__ Wlo) {
    int i = blockIdx.x * 256 + threadIdx.x;   // 0..32767
    int o = i >> 8, k = i & 255;
    float v = (k < 128) ? Wl[o * FF + k] : Wr[o * FF + k - 128];
    uint_t u = __float_as_uint(v);
    float hif = __uint_as_float(u & 0xffff0000u);
    float lof = v - hif;
    Whi[i] = (ushort_t)(u >> 16);
    Wlo[i] = (ushort_t)(__float_as_uint(lof) >> 16);
}

// ---------------- per-node mean gather: one wave/node, float4, 8 loads in flight ----
__global__ __launch_bounds__(256) void k_gather(const float* __restrict__ x,
                                                const int* __restrict__ ssrc,
                                                const int* __restrict__ starts,
                                                float* __restrict__ mean) {
    int n    = blockIdx.x * 4 + (threadIdx.x >> 6);
    int lane = threadIdx.x & 63;
    int half = lane >> 5;            // neighbor parity
    int l32  = lane & 31;            // feature quad: f = l32*4
    int d0 = starts[n], d1 = starts[n + 1];

    f32x4 a0 = (f32x4){0.f, 0.f, 0.f, 0.f};
    f32x4 a1 = (f32x4){0.f, 0.f, 0.f, 0.f};
    f32x4 a2 = (f32x4){0.f, 0.f, 0.f, 0.f};
    f32x4 a3 = (f32x4){0.f, 0.f, 0.f, 0.f};
    int e = d0 + half;
    for (; e + 6 < d1; e += 8) {
        int s0 = ssrc[e];
        int s1 = ssrc[e + 2];
        int s2 = ssrc[e + 4];
        int s3 = ssrc[e + 6];
        a0 += *(const f32x4*)(x + (size_t)s0 * FF + l32 * 4);
        a1 += *(const f32x4*)(x + (size_t)s1 * FF + l32 * 4);
        a2 += *(const f32x4*)(x + (size_t)s2 * FF + l32 * 4);
        a3 += *(const f32x4*)(x + (size_t)s3 * FF + l32 * 4);
    }
    if (e < d1) {
        a0 += *(const f32x4*)(x + (size_t)ssrc[e] * FF + l32 * 4);
        e += 2;
    }
    if (e < d1) {
        a1 += *(const f32x4*)(x + (size_t)ssrc[e] * FF + l32 * 4);
        e += 2;
    }
    if (e < d1) {
        a2 += *(const f32x4*)(x + (size_t)ssrc[e] * FF + l32 * 4);
    }
    f32x4 acc = (a0 + a1) + (a2 + a3);
    f32x4 oth;
#pragma unroll
    for (int j = 0; j < 4; ++j) oth[j] = __shfl_xor(acc[j], 32);
    acc += oth;
    if (half == 0) {
        float inv = 1.0f / fmaxf((float)(d1 - d0), 1.0f);
        acc *= inv;
        *(f32x4*)(mean + (size_t)n * FF + l32 * 4) = acc;
    }
}

// ---------------- h = [mean||x] @ [Wl||Wr]^T + bl  via MFMA, B fully in LDS ----
__global__ __launch_bounds__(512, 1) void k_gemm_mfma(const float* __restrict__ mean,
                                                      const float* __restrict__ x,
                                                      const ushort_t* __restrict__ Whi,
                                                      const ushort_t* __restrict__ Wlo,
                                                      const float* __restrict__ blv,
                                                      float* __restrict__ h,
                                                      float* __restrict__ pstats) {
    __shared__ __align__(16) ushort_t Bst[65536];   // 128 KB
    __shared__ float ls1[8][128], ls2[8][128];      // 8 KB
    const int tid = threadIdx.x;

#pragma unroll
    for (int i = 0; i < 16; ++i) {
        int q = tid + i * 512;          // cell id = c*256 + idx
        int c = q >> 8, idx = q & 255;
        const ushort_t* src = (idx < 128) ? (Whi + idx * 256 + c * 8)
                                          : (Wlo + (idx - 128) * 256 + c * 8);
        *(bf16x8*)&Bst[q * 8] = *(const bf16x8*)src;
    }
    __syncthreads();

    const int w    = tid >> 6;
    const int lane = tid & 63;
    const int kof  = (lane >> 4) * 8;
    const int bcol = lane & 15;
    const int r0   = blockIdx.x * 256 + w * 32;

    const float* __restrict__ pm0 = mean + (size_t)(r0 + (lane & 15)) * FF + kof;
    const float* __restrict__ px0 = x    + (size_t)(r0 + (lane & 15)) * FF + kof;
    const float* __restrict__ pm1 = pm0 + 16 * FF;
    const float* __restrict__ px1 = px0 + 16 * FF;

    f32x4 acc[2][8];
#pragma unroll
    for (int rt = 0; rt < 2; ++rt)
#pragma unroll
        for (int n = 0; n < 8; ++n) acc[rt][n] = (f32x4){0.f, 0.f, 0.f, 0.f};

    f32x4 a0c[2], a1c[2];
    a0c[0] = *(const f32x4*)pm0;
    a1c[0] = *(const f32x4*)(pm0 + 4);
    a0c[1] = *(const f32x4*)pm1;
    a1c[1] = *(const f32x4*)(pm1 + 4);

#pragma unroll
    for (int ks = 0; ks < 8; ++ks) {
        const int k0 = ks * 32;
        f32x4 a0n[2], a1n[2];
        if (ks < 7) {
            const int kn = k0 + 32;
            const float* pn0 = (kn < 128) ? (pm0 + kn) : (px0 + (kn - 128));
            const float* pn1 = (kn < 128) ? (pm1 + kn) : (px1 + (kn - 128));
            a0n[0] = *(const f32x4*)pn0;
            a1n[0] = *(const f32x4*)(pn0 + 4);
            a0n[1] = *(const f32x4*)pn1;
            a1n[1] = *(const f32x4*)(pn1 + 4);
        }
        bf16x8 ah[2], al[2];
#pragma unroll
        for (int rt = 0; rt < 2; ++rt)
#pragma unroll
            for (int e = 0; e < 8; ++e) {
                float v = (e < 4) ? a0c[rt][e] : a1c[rt][e - 4];
                uint_t u = __float_as_uint(v);
                float hif = __uint_as_float(u & 0xffff0000u);
                float lof = v - hif;
                ah[rt][e] = (short)(u >> 16);
                al[rt][e] = (short)(__float_as_uint(lof) >> 16);
            }
        const int cbase = (ks * 4 + (lane >> 4)) * 256;
#pragma unroll
        for (int n = 0; n < 8; ++n) {
            int oo = n * 16 + bcol;
            bf16x8 bh = *(const bf16x8*)&Bst[(cbase + oo) * 8];
            bf16x8 bl = *(const bf16x8*)&Bst[(cbase + 128 + oo) * 8];
#pragma unroll
            for (int rt = 0; rt < 2; ++rt) {
                acc[rt][n] = __builtin_amdgcn_mfma_f32_16x16x32_bf16(ah[rt], bh, acc[rt][n], 0, 0, 0);
                acc[rt][n] = __builtin_amdgcn_mfma_f32_16x16x32_bf16(ah[rt], bl, acc[rt][n], 0, 0, 0);
                acc[rt][n] = __builtin_amdgcn_mfma_f32_16x16x32_bf16(al[rt], bh, acc[rt][n], 0, 0, 0);
            }
        }
        a0c[0] = a0n[0]; a1c[0] = a1n[0];
        a0c[1] = a0n[1]; a1c[1] = a1n[1];
    }

#pragma unroll
    for (int n = 0; n < 8; ++n) {
        int col = n * 16 + bcol;
        float b = blv[col];
        float p1 = 0.f, p2 = 0.f;
#pragma unroll
        for (int rt = 0; rt < 2; ++rt) {
            int orow = r0 + rt * 16 + (lane >> 4) * 4;
#pragma unroll
            for (int j = 0; j < 4; ++j) {
                float v = acc[rt][n][j] + b;
                h[(size_t)(orow + j) * FF + col] = v;
                p1 += v;
                p2 += v * v;
            }
        }
        p1 += __shfl_xor(p1, 16); p1 += __shfl_xor(p1, 32);
        p2 += __shfl_xor(p2, 16); p2 += __shfl_xor(p2, 32);
        if (lane < 16) { ls1[w][col] = p1; ls2[w][col] = p2; }
    }
    __syncthreads();
    if (tid < 128) {
        float a = 0.f, b2 = 0.f;
#pragma unroll
        for (int ww = 0; ww < 8; ++ww) {
            a  += ls1[ww][tid];
            b2 += ls2[ww][tid];
        }
        pstats[(size_t)blockIdx.x * 256 + tid]       = a;
        pstats[(size_t)blockIdx.x * 256 + 128 + tid] = b2;
    }
}

// ---------------- deterministic 2-stage stats reduction (256 partials) ----------------
__global__ __launch_bounds__(256) void k_red1(const float* __restrict__ pstats,
                                              float* __restrict__ pr) {
    int t = threadIdx.x;
    int r = blockIdx.x;             // 0..15
    float s = 0.f;
    for (int i = 0; i < 16; ++i)
        s += pstats[(size_t)(r * 16 + i) * 256 + t];
    pr[r * 256 + t] = s;
}

__global__ __launch_bounds__(256) void k_red2(const float* __restrict__ pr,
                                              float* __restrict__ stats) {
    int t = threadIdx.x;
    float s = 0.f;
    for (int r = 0; r < 16; ++r)
        s += pr[r * 256 + t];
    stats[t] = s;
}

// ---------------- score (BN params inline) ----------------
__global__ __launch_bounds__(256) void k_score(const float* __restrict__ h,
                                               const float* __restrict__ stats,
                                               const float* __restrict__ gamma,
                                               const float* __restrict__ beta,
                                               const float* __restrict__ attn,
                                               float* __restrict__ score) {
    int tid = threadIdx.x;
    int l32 = tid & 31;
    int n   = blockIdx.x * 8 + (tid >> 5);
    int f0  = l32 * 4;
    float4 su = *(const float4*)&stats[f0];
    float4 sq = *(const float4*)&stats[128 + f0];
    float4 g4 = *(const float4*)&gamma[f0];
    float4 b4 = *(const float4*)&beta[f0];
    float4 a4 = *(const float4*)&attn[f0];
    float an = a4.x * a4.x + a4.y * a4.y + a4.z * a4.z + a4.w * a4.w;
#pragma unroll
    for (int off = 16; off > 0; off >>= 1) an += __shfl_xor(an, off);
    float inva = 1.0f / sqrtf(an);
    float invN = 1.0f / (float)NN;
    float m0 = su.x * invN, m1 = su.y * invN, m2 = su.z * invN, m3 = su.w * invN;
    float sc0 = g4.x / sqrtf(sq.x * invN - m0 * m0 + EPSBN);
    float sc1 = g4.y / sqrtf(sq.y * invN - m1 * m1 + EPSBN);
    float sc2 = g4.z / sqrtf(sq.z * invN - m2 * m2 + EPSBN);
    float sc3 = g4.w / sqrtf(sq.w * invN - m3 * m3 + EPSBN);
    float4 hv = *(const float4*)&h[(size_t)n * FF + f0];
    float v0 = fmaxf((hv.x - m0) * sc0 + b4.x, 0.f);
    float v1 = fmaxf((hv.y - m1) * sc1 + b4.y, 0.f);
    float v2 = fmaxf((hv.z - m2) * sc2 + b4.z, 0.f);
    float v3 = fmaxf((hv.w - m3) * sc3 + b4.w, 0.f);
    float s = (v0 * a4.x + v1 * a4.y + v2 * a4.z + v3 * a4.w) * inva;
#pragma unroll
    for (int off = 16; off > 0; off >>= 1) s += __shfl_xor(s, off);
    if (l32 == 0) score[n] = s;
}

// ---------------- per-graph bitonic sort: register/shfl for j<64, LDS for j>=64 ----
// Same comparator network as before (bit-identical result; keys unique).
__global__ __launch_bounds__(1024) void k_topk(const float* __restrict__ score,
                                               int* __restrict__ nmap,
                                               int* __restrict__ plist,
                                               float* __restrict__ out_batch) {
    __shared__ unsigned long long sh[PERG];
    int b = blockIdx.x;
    int t = threadIdx.x;
    float s = score[b * PERG + t];
    unsigned u = __float_as_uint(s);
    u = (u & 0x80000000u) ? ~u : (u | 0x80000000u);
    unsigned long long key = ((unsigned long long)u << 10) | (unsigned long long)(1023 - t);

    for (int k = 2; k <= PERG; k <<= 1) {
        bool asc = (t & k) != 0;
        for (int j = k >> 1; j > 0; j >>= 1) {
            bool upper = (t & j) != 0;
            unsigned long long other;
            if (j >= 64) {
                __syncthreads();
                sh[t] = key;
                __syncthreads();
                other = sh[t ^ j];
            } else {
                other = __shfl_xor(key, j, 64);
            }
            bool takeMax = (asc == upper);
            key = takeMax ? (key > other ? key : other)
                          : (key < other ? key : other);
        }
    }

    if (t < KKEEP) {
        int idx = 1023 - (int)(key & 1023ull);
        int g   = b * PERG + idx;
        int nid = b * KKEEP + t;
        plist[nid]     = g;
        nmap[g]        = nid;
        out_batch[nid] = (float)b;
    }
}

// ---------------- hp = BNrelu(h[perm]) * tanh(score[perm]) + fused pool partials ----
__global__ __launch_bounds__(256) void k_hp2(const float* __restrict__ h,
                                             const float* __restrict__ score,
                                             const int* __restrict__ plist,
                                             const float* __restrict__ stats,
                                             const float* __restrict__ gamma,
                                             const float* __restrict__ beta,
                                             float* __restrict__ out_hp,
                                             float* __restrict__ pflat) {
    int b   = blockIdx.x;             // 0..1279
    int g   = b / NCH, c = b % NCH;
    int tid = threadIdx.x;
    int f   = tid & 127, half = tid >> 7;
    int r0  = g * KKEEP + c * CHUNK;

    __shared__ float tts[CHUNK];
    __shared__ int   gl[CHUNK];
    if (tid < CHUNK) {
        int gg = plist[r0 + tid];
        gl[tid]  = gg;
        tts[tid] = tanhf(score[gg]);
    }
    __syncthreads();

    float invN = 1.0f / (float)NN;
    float m  = stats[f] * invN;
    float sc = gamma[f] / sqrtf(stats[128 + f] * invN - m * m + EPSBN);
    float bb = beta[f];
    float s = 0.f, mx = -INFINITY;
    for (int i = half; i < CHUNK; i += 2) {
        int gg = gl[i];
        float v = fmaxf((h[(size_t)gg * FF + f] - m) * sc + bb, 0.f) * tts[i];
        out_hp[(size_t)(r0 + i) * FF + f] = v;
        s += v;
        mx = fmaxf(mx, v);
    }
    __shared__ float ls[256], lm[256];
    ls[tid] = s;
    lm[tid] = mx;
    __syncthreads();
    if (half == 0) {
        pflat[(size_t)b * 256 + f]       = ls[f] + ls[128 + f];
        pflat[(size_t)b * 256 + 128 + f] = fmaxf(lm[f], lm[128 + f]);
    }
}

// ---------------- final per-graph combine (fixed order) ----------------
__global__ __launch_bounds__(256) void k_flat2(const float* __restrict__ pflat,
                                               float* __restrict__ out_flat) {
    int b = blockIdx.x;
    int t = threadIdx.x;
    if (t < 128) {
        float s = 0.f;
        for (int c = 0; c < NCH; ++c)
            s += pflat[(size_t)(b * NCH + c) * 256 + t];
        out_flat[b * 256 + t] = s;
    } else {
        int f = t - 128;
        float m = -INFINITY;
        for (int c = 0; c < NCH; ++c)
            m = fmaxf(m, pflat[(size_t)(b * NCH + c) * 256 + 128 + f]);
        out_flat[b * 256 + 128 + f] = m;
    }
}

// ---------------- edge reindex ----------------
__global__ __launch_bounds__(256) void k_edge(const int* __restrict__ ei,
                                              const int* __restrict__ nmap,
                                              float* __restrict__ out_edge) {
    int e = blockIdx.x * 256 + threadIdx.x;
    if (e >= EE) return;
    int s  = ei[e];
    int d  = ei[EE + e];
    int ns = nmap[s];
    int nd = nmap[d];
    bool keep = (ns >= 0) && (nd >= 0);
    out_edge[e]      = keep ? (float)ns : -1.0f;
    out_edge[EE + e] = keep ? (float)nd : -1.0f;
}

extern "C" void kernel_launch(void* const* d_in, const int* in_sizes, int n_in,
                              void* d_out, int out_size, void* d_ws, size_t ws_size,
                              hipStream_t stream) {
    const float* x    = (const float*)d_in[0];
    const int*   ei   = (const int*)d_in[1];
    const float* Wl   = (const float*)d_in[3];
    const float* bl   = (const float*)d_in[4];
    const float* Wr   = (const float*)d_in[5];
    const float* gam  = (const float*)d_in[6];
    const float* bet  = (const float*)d_in[7];
    const float* attn = (const float*)d_in[8];

    // workspace layout
    float*    mean  = (float*)d_ws;                    // NN*FF
    float*    h     = mean + (size_t)NN * FF;          // NN*FF
    float*    score = h + (size_t)NN * FF;             // NN    (aliased: deg)
    int*      nmap  = (int*)(score + NN);              // NN    (aliased: spart)
    int*      plist = nmap + NN;                       // BBG*KKEEP
    float*    stats = (float*)(plist + BBG * KKEEP);   // 256
    ushort_t* Whi   = (ushort_t*)(stats + 256);        // 32768
    ushort_t* Wlo   = Whi + 32768;                     // 32768
    int*      starts = (int*)(Wlo + 32768);            // NN+1
    int*      cursor = starts + NN + 1;                // NN
    int*      ssrc   = cursor + NN;                    // EE
    int*      bsum   = ssrc + EE;                      // 256
    int*      boff   = bsum + 256;                     // 256
    float*    pstats = (float*)(boff + 256);           // 256*256
    float*    pr     = pstats + 256 * 256;             // 16*256
    float*    pflat  = pr + 16 * 256;                  // 1280*256

    int* deg   = (int*)score;   // dead before k_score writes score
    int* spart = (int*)nmap;    // dead before nmap memset

    // output layout (all float32)
    float* out       = (float*)d_out;
    float* out_hp    = out;                                // 52480*128
    float* out_flat  = out_hp + (size_t)BBG * KKEEP * FF;  // 64*256
    float* out_edge  = out_flat + BBG * 256;               // 2*EE
    float* out_batch = out_edge + 2 * EE;                  // 52480

    hipMemsetAsync(deg, 0, (size_t)NN * sizeof(int), stream);

    k_wcvt<<<128, 256, 0, stream>>>(Wl, Wr, Whi, Wlo);
    k_deg<<<EE / 256, 256, 0, stream>>>(ei, deg);
    k_scan1<<<256, 256, 0, stream>>>(deg, spart, bsum);
    k_scan2<<<1, 256, 0, stream>>>(bsum, boff);
    k_scan3<<<256, 256, 0, stream>>>(deg, spart, boff, starts, cursor);
    k_scatter<<<EE / 256, 256, 0, stream>>>(ei, cursor, ssrc);
    k_sortnb<<<NN / 256, 256, 0, stream>>>(starts, ssrc);

    hipMemsetAsync(nmap, 0xFF, (size_t)NN * sizeof(int), stream);  // spart dead now

    k_gather<<<NN / 4, 256, 0, stream>>>(x, ssrc, starts, mean);
    k_gemm_mfma<<<NN / 256, 512, 0, stream>>>(mean, x, Whi, Wlo, bl, h, pstats);
    k_red1<<<16, 256, 0, stream>>>(pstats, pr);
    k_red2<<<1, 256, 0, stream>>>(pr, stats);
    k_score<<<NN / 8, 256, 0, stream>>>(h, stats, gam, bet, attn, score);
    k_topk<<<BBG, 1024, 0, stream>>>(score, nmap, plist, out_batch);
    k_hp2<<<BBG * NCH, 256, 0, stream>>>(h, score, plist, stats, gam, bet, out_hp, pflat);
    k_flat2<<<BBG, 256, 0, stream>>>(pflat, out_flat);
    k_edge<<<EE / 256, 256, 0, stream>>>(ei, nmap, out_edge);
}

// Round 15
// 208.415 us; speedup vs baseline: 1.2202x; 1.0215x over previous
//
#include <hip/hip_runtime.h>
#include <hip/hip_bf16.h>
#include <math.h>

#define NN    65536
#define EE    524288
#define BBG   64
#define PERG  1024
#define KKEEP 820
#define FF    128
#define EPSBN 1e-5f
#define CHUNK 41
#define NCH   20

typedef __attribute__((ext_vector_type(8))) short bf16x8;
typedef __attribute__((ext_vector_type(4))) float f32x4;
typedef unsigned short ushort_t;
typedef unsigned int uint_t;

// ---------------- fused: W split (blocks 0..127) + degree histogram (rest) ----------------
__global__ __launch_bounds__(256) void k_init(const float* __restrict__ Wl,
                                              const float* __restrict__ Wr,
                                              ushort_t* __restrict__ Whi,
                                              ushort_t* __restrict__ Wlo,
                                              const int* __restrict__ ei,
                                              int* __restrict__ deg) {
    int blk = blockIdx.x;
    int tid = threadIdx.x;
    if (blk < 128) {
        int i = blk * 256 + tid;              // 0..32767
        int o = i >> 8, k = i & 255;
        float v = (k < 128) ? Wl[o * FF + k] : Wr[o * FF + k - 128];
        uint_t u = __float_as_uint(v);
        float hif = __uint_as_float(u & 0xffff0000u);
        float lof = v - hif;
        Whi[i] = (ushort_t)(u >> 16);
        Wlo[i] = (ushort_t)(__float_as_uint(lof) >> 16);
    } else {
        int e = (blk - 128) * 256 + tid;
        if (e < EE) atomicAdd(&deg[ei[EE + e]], 1);
    }
}

// ---------------- scan stage 1: per-block inclusive scan + block sums ----------------
__global__ __launch_bounds__(256) void k_scan1(const int* __restrict__ deg,
                                               int* __restrict__ spart,
                                               int* __restrict__ bsum) {
    int t = threadIdx.x;
    int i = blockIdx.x * 256 + t;
    __shared__ int sh[256];
    int v = deg[i];
    sh[t] = v;
    __syncthreads();
    for (int o = 1; o < 256; o <<= 1) {
        int u = (t >= o) ? sh[t - o] : 0;
        __syncthreads();
        sh[t] += u;
        __syncthreads();
    }
    spart[i] = sh[t];
    if (t == 255) bsum[blockIdx.x] = sh[255];
}

// ---------------- scan stages 2+3 fused: every block scans bsum, emits starts ----------------
__global__ __launch_bounds__(256) void k_scan23(const int* __restrict__ deg,
                                                const int* __restrict__ spart,
                                                const int* __restrict__ bsum,
                                                int* __restrict__ starts,
                                                int* __restrict__ cursor) {
    int t = threadIdx.x;
    __shared__ int sh[256];
    __shared__ int orig[256];
    int v = bsum[t];
    orig[t] = v;
    sh[t] = v;
    __syncthreads();
    for (int o = 1; o < 256; o <<= 1) {
        int u = (t >= o) ? sh[t - o] : 0;
        __syncthreads();
        sh[t] += u;
        __syncthreads();
    }
    int bo = sh[blockIdx.x] - orig[blockIdx.x];   // exclusive block offset
    int i  = blockIdx.x * 256 + t;
    int st = spart[i] - deg[i] + bo;
    starts[i] = st;
    cursor[i] = st;
    if (i == 0) starts[NN] = EE;
}

// ---------------- scatter edges into CSR ----------------
__global__ __launch_bounds__(256) void k_scatter(const int* __restrict__ ei,
                                                 int* __restrict__ cursor,
                                                 int* __restrict__ ssrc) {
    int e = blockIdx.x * 256 + threadIdx.x;
    if (e >= EE) return;
    int s = ei[e];
    int d = ei[EE + e];
    int pos = atomicAdd(&cursor[d], 1);
    ssrc[pos] = s;
}

// ---------------- per-node neighbor-list sort: make ssrc deterministic ----------------
__global__ __launch_bounds__(256) void k_sortnb(const int* __restrict__ starts,
                                                int* __restrict__ ssrc) {
    int n = blockIdx.x * 256 + threadIdx.x;
    if (n >= NN) return;
    int d0 = starts[n], d1 = starts[n + 1];
    for (int i = d0 + 1; i < d1; ++i) {
        int key = ssrc[i];
        int j = i - 1;
        while (j >= d0 && ssrc[j] > key) {
            ssrc[j + 1] = ssrc[j];
            --j;
        }
        ssrc[j + 1] = key;
    }
}

// ---------------- per-node mean gather: one wave/node, float4, 8 loads in flight ----
__global__ __launch_bounds__(256) void k_gather(const float* __restrict__ x,
                                                const int* __restrict__ ssrc,
                                                const int* __restrict__ starts,
                                                float* __restrict__ mean) {
    int n    = blockIdx.x * 4 + (threadIdx.x >> 6);
    int lane = threadIdx.x & 63;
    int half = lane >> 5;            // neighbor parity
    int l32  = lane & 31;            // feature quad: f = l32*4
    int d0 = starts[n], d1 = starts[n + 1];

    f32x4 a0 = (f32x4){0.f, 0.f, 0.f, 0.f};
    f32x4 a1 = (f32x4){0.f, 0.f, 0.f, 0.f};
    f32x4 a2 = (f32x4){0.f, 0.f, 0.f, 0.f};
    f32x4 a3 = (f32x4){0.f, 0.f, 0.f, 0.f};
    int e = d0 + half;
    for (; e + 6 < d1; e += 8) {
        int s0 = ssrc[e];
        int s1 = ssrc[e + 2];
        int s2 = ssrc[e + 4];
        int s3 = ssrc[e + 6];
        a0 += *(const f32x4*)(x + (size_t)s0 * FF + l32 * 4);
        a1 += *(const f32x4*)(x + (size_t)s1 * FF + l32 * 4);
        a2 += *(const f32x4*)(x + (size_t)s2 * FF + l32 * 4);
        a3 += *(const f32x4*)(x + (size_t)s3 * FF + l32 * 4);
    }
    if (e < d1) {
        a0 += *(const f32x4*)(x + (size_t)ssrc[e] * FF + l32 * 4);
        e += 2;
    }
    if (e < d1) {
        a1 += *(const f32x4*)(x + (size_t)ssrc[e] * FF + l32 * 4);
        e += 2;
    }
    if (e < d1) {
        a2 += *(const f32x4*)(x + (size_t)ssrc[e] * FF + l32 * 4);
    }
    f32x4 acc = (a0 + a1) + (a2 + a3);
    f32x4 oth;
#pragma unroll
    for (int j = 0; j < 4; ++j) oth[j] = __shfl_xor(acc[j], 32);
    acc += oth;
    if (half == 0) {
        float inv = 1.0f / fmaxf((float)(d1 - d0), 1.0f);
        acc *= inv;
        *(f32x4*)(mean + (size_t)n * FF + l32 * 4) = acc;
    }
}

// ---------------- h = [mean||x] @ [Wl||Wr]^T + bl  via MFMA, B fully in LDS ----
__global__ __launch_bounds__(512, 1) void k_gemm_mfma(const float* __restrict__ mean,
                                                      const float* __restrict__ x,
                                                      const ushort_t* __restrict__ Whi,
                                                      const ushort_t* __restrict__ Wlo,
                                                      const float* __restrict__ blv,
                                                      float* __restrict__ h,
                                                      float* __restrict__ pstats) {
    __shared__ __align__(16) ushort_t Bst[65536];   // 128 KB
    __shared__ float ls1[8][128], ls2[8][128];      // 8 KB
    const int tid = threadIdx.x;

#pragma unroll
    for (int i = 0; i < 16; ++i) {
        int q = tid + i * 512;          // cell id = c*256 + idx
        int c = q >> 8, idx = q & 255;
        const ushort_t* src = (idx < 128) ? (Whi + idx * 256 + c * 8)
                                          : (Wlo + (idx - 128) * 256 + c * 8);
        *(bf16x8*)&Bst[q * 8] = *(const bf16x8*)src;
    }
    __syncthreads();

    const int w    = tid >> 6;
    const int lane = tid & 63;
    const int kof  = (lane >> 4) * 8;
    const int bcol = lane & 15;
    const int r0   = blockIdx.x * 256 + w * 32;

    const float* __restrict__ pm0 = mean + (size_t)(r0 + (lane & 15)) * FF + kof;
    const float* __restrict__ px0 = x    + (size_t)(r0 + (lane & 15)) * FF + kof;
    const float* __restrict__ pm1 = pm0 + 16 * FF;
    const float* __restrict__ px1 = px0 + 16 * FF;

    f32x4 acc[2][8];
#pragma unroll
    for (int rt = 0; rt < 2; ++rt)
#pragma unroll
        for (int n = 0; n < 8; ++n) acc[rt][n] = (f32x4){0.f, 0.f, 0.f, 0.f};

    f32x4 a0c[2], a1c[2];
    a0c[0] = *(const f32x4*)pm0;
    a1c[0] = *(const f32x4*)(pm0 + 4);
    a0c[1] = *(const f32x4*)pm1;
    a1c[1] = *(const f32x4*)(pm1 + 4);

#pragma unroll
    for (int ks = 0; ks < 8; ++ks) {
        const int k0 = ks * 32;
        f32x4 a0n[2], a1n[2];
        if (ks < 7) {
            const int kn = k0 + 32;
            const float* pn0 = (kn < 128) ? (pm0 + kn) : (px0 + (kn - 128));
            const float* pn1 = (kn < 128) ? (pm1 + kn) : (px1 + (kn - 128));
            a0n[0] = *(const f32x4*)pn0;
            a1n[0] = *(const f32x4*)(pn0 + 4);
            a0n[1] = *(const f32x4*)pn1;
            a1n[1] = *(const f32x4*)(pn1 + 4);
        }
        bf16x8 ah[2], al[2];
#pragma unroll
        for (int rt = 0; rt < 2; ++rt)
#pragma unroll
            for (int e = 0; e < 8; ++e) {
                float v = (e < 4) ? a0c[rt][e] : a1c[rt][e - 4];
                uint_t u = __float_as_uint(v);
                float hif = __uint_as_float(u & 0xffff0000u);
                float lof = v - hif;
                ah[rt][e] = (short)(u >> 16);
                al[rt][e] = (short)(__float_as_uint(lof) >> 16);
            }
        const int cbase = (ks * 4 + (lane >> 4)) * 256;
#pragma unroll
        for (int n = 0; n < 8; ++n) {
            int oo = n * 16 + bcol;
            bf16x8 bh = *(const bf16x8*)&Bst[(cbase + oo) * 8];
            bf16x8 bl = *(const bf16x8*)&Bst[(cbase + 128 + oo) * 8];
#pragma unroll
            for (int rt = 0; rt < 2; ++rt) {
                acc[rt][n] = __builtin_amdgcn_mfma_f32_16x16x32_bf16(ah[rt], bh, acc[rt][n], 0, 0, 0);
                acc[rt][n] = __builtin_amdgcn_mfma_f32_16x16x32_bf16(ah[rt], bl, acc[rt][n], 0, 0, 0);
                acc[rt][n] = __builtin_amdgcn_mfma_f32_16x16x32_bf16(al[rt], bh, acc[rt][n], 0, 0, 0);
            }
        }
        a0c[0] = a0n[0]; a1c[0] = a1n[0];
        a0c[1] = a0n[1]; a1c[1] = a1n[1];
    }

#pragma unroll
    for (int n = 0; n < 8; ++n) {
        int col = n * 16 + bcol;
        float b = blv[col];
        float p1 = 0.f, p2 = 0.f;
#pragma unroll
        for (int rt = 0; rt < 2; ++rt) {
            int orow = r0 + rt * 16 + (lane >> 4) * 4;
#pragma unroll
            for (int j = 0; j < 4; ++j) {
                float v = acc[rt][n][j] + b;
                h[(size_t)(orow + j) * FF + col] = v;
                p1 += v;
                p2 += v * v;
            }
        }
        p1 += __shfl_xor(p1, 16); p1 += __shfl_xor(p1, 32);
        p2 += __shfl_xor(p2, 16); p2 += __shfl_xor(p2, 32);
        if (lane < 16) { ls1[w][col] = p1; ls2[w][col] = p2; }
    }
    __syncthreads();
    if (tid < 128) {
        float a = 0.f, b2 = 0.f;
#pragma unroll
        for (int ww = 0; ww < 8; ++ww) {
            a  += ls1[ww][tid];
            b2 += ls2[ww][tid];
        }
        pstats[(size_t)blockIdx.x * 256 + tid]       = a;
        pstats[(size_t)blockIdx.x * 256 + 128 + tid] = b2;
    }
}

// ---------------- stats reduction: one block, bit-identical nested 16x16 order ----------------
__global__ __launch_bounds__(256) void k_red(const float* __restrict__ pstats,
                                             float* __restrict__ stats) {
    int t = threadIdx.x;
    float s = 0.f;
    for (int r = 0; r < 16; ++r) {
        float g = 0.f;
        for (int i = 0; i < 16; ++i)
            g += pstats[(size_t)(r * 16 + i) * 256 + t];
        s += g;
    }
    stats[t] = s;
}

// ---------------- score (BN params inline) ----------------
__global__ __launch_bounds__(256) void k_score(const float* __restrict__ h,
                                               const float* __restrict__ stats,
                                               const float* __restrict__ gamma,
                                               const float* __restrict__ beta,
                                               const float* __restrict__ attn,
                                               float* __restrict__ score) {
    int tid = threadIdx.x;
    int l32 = tid & 31;
    int n   = blockIdx.x * 8 + (tid >> 5);
    int f0  = l32 * 4;
    float4 su = *(const float4*)&stats[f0];
    float4 sq = *(const float4*)&stats[128 + f0];
    float4 g4 = *(const float4*)&gamma[f0];
    float4 b4 = *(const float4*)&beta[f0];
    float4 a4 = *(const float4*)&attn[f0];
    float an = a4.x * a4.x + a4.y * a4.y + a4.z * a4.z + a4.w * a4.w;
#pragma unroll
    for (int off = 16; off > 0; off >>= 1) an += __shfl_xor(an, off);
    float inva = 1.0f / sqrtf(an);
    float invN = 1.0f / (float)NN;
    float m0 = su.x * invN, m1 = su.y * invN, m2 = su.z * invN, m3 = su.w * invN;
    float sc0 = g4.x / sqrtf(sq.x * invN - m0 * m0 + EPSBN);
    float sc1 = g4.y / sqrtf(sq.y * invN - m1 * m1 + EPSBN);
    float sc2 = g4.z / sqrtf(sq.z * invN - m2 * m2 + EPSBN);
    float sc3 = g4.w / sqrtf(sq.w * invN - m3 * m3 + EPSBN);
    float4 hv = *(const float4*)&h[(size_t)n * FF + f0];
    float v0 = fmaxf((hv.x - m0) * sc0 + b4.x, 0.f);
    float v1 = fmaxf((hv.y - m1) * sc1 + b4.y, 0.f);
    float v2 = fmaxf((hv.z - m2) * sc2 + b4.z, 0.f);
    float v3 = fmaxf((hv.w - m3) * sc3 + b4.w, 0.f);
    float s = (v0 * a4.x + v1 * a4.y + v2 * a4.z + v3 * a4.w) * inva;
#pragma unroll
    for (int off = 16; off > 0; off >>= 1) s += __shfl_xor(s, off);
    if (l32 == 0) score[n] = s;
}

// ---------------- per-graph bitonic sort: register/shfl j<64, LDS j>=64 ----------------
// Writes ALL nmap entries (kept -> nid, dropped -> -1): no nmap memset needed.
__global__ __launch_bounds__(1024) void k_topk(const float* __restrict__ score,
                                               int* __restrict__ nmap,
                                               int* __restrict__ plist,
                                               float* __restrict__ out_batch) {
    __shared__ unsigned long long sh[PERG];
    int b = blockIdx.x;
    int t = threadIdx.x;
    float s = score[b * PERG + t];
    unsigned u = __float_as_uint(s);
    u = (u & 0x80000000u) ? ~u : (u | 0x80000000u);
    unsigned long long key = ((unsigned long long)u << 10) | (unsigned long long)(1023 - t);

    for (int k = 2; k <= PERG; k <<= 1) {
        bool asc = (t & k) != 0;
        for (int j = k >> 1; j > 0; j >>= 1) {
            bool upper = (t & j) != 0;
            unsigned long long other;
            if (j >= 64) {
                __syncthreads();
                sh[t] = key;
                __syncthreads();
                other = sh[t ^ j];
            } else {
                other = __shfl_xor(key, j, 64);
            }
            bool takeMax = (asc == upper);
            key = takeMax ? (key > other ? key : other)
                          : (key < other ? key : other);
        }
    }

    int idx = 1023 - (int)(key & 1023ull);
    int g   = b * PERG + idx;
    if (t < KKEEP) {
        int nid = b * KKEEP + t;
        plist[nid]     = g;
        nmap[g]        = nid;
        out_batch[nid] = (float)b;
    } else {
        nmap[g] = -1;
    }
}

// ---------------- hp = BNrelu(h[perm]) * tanh(score[perm]) + fused pool partials ----
__global__ __launch_bounds__(256) void k_hp2(const float* __restrict__ h,
                                             const float* __restrict__ score,
                                             const int* __restrict__ plist,
                                             const float* __restrict__ stats,
                                             const float* __restrict__ gamma,
                                             const float* __restrict__ beta,
                                             float* __restrict__ out_hp,
                                             float* __restrict__ pflat) {
    int b   = blockIdx.x;             // 0..1279
    int g   = b / NCH, c = b % NCH;
    int tid = threadIdx.x;
    int f   = tid & 127, half = tid >> 7;
    int r0  = g * KKEEP + c * CHUNK;

    __shared__ float tts[CHUNK];
    __shared__ int   gl[CHUNK];
    if (tid < CHUNK) {
        int gg = plist[r0 + tid];
        gl[tid]  = gg;
        tts[tid] = tanhf(score[gg]);
    }
    __syncthreads();

    float invN = 1.0f / (float)NN;
    float m  = stats[f] * invN;
    float sc = gamma[f] / sqrtf(stats[128 + f] * invN - m * m + EPSBN);
    float bb = beta[f];
    float s = 0.f, mx = -INFINITY;
    for (int i = half; i < CHUNK; i += 2) {
        int gg = gl[i];
        float v = fmaxf((h[(size_t)gg * FF + f] - m) * sc + bb, 0.f) * tts[i];
        out_hp[(size_t)(r0 + i) * FF + f] = v;
        s += v;
        mx = fmaxf(mx, v);
    }
    __shared__ float ls[256], lm[256];
    ls[tid] = s;
    lm[tid] = mx;
    __syncthreads();
    if (half == 0) {
        pflat[(size_t)b * 256 + f]       = ls[f] + ls[128 + f];
        pflat[(size_t)b * 256 + 128 + f] = fmaxf(lm[f], lm[128 + f]);
    }
}

// ---------------- fused tail: per-graph combine (blocks 0..63) + edge reindex ----------------
__global__ __launch_bounds__(256) void k_tail(const float* __restrict__ pflat,
                                              float* __restrict__ out_flat,
                                              const int* __restrict__ ei,
                                              const int* __restrict__ nmap,
                                              float* __restrict__ out_edge) {
    int blk = blockIdx.x;
    int t   = threadIdx.x;
    if (blk < BBG) {
        int b = blk;
        if (t < 128) {
            float s = 0.f;
            for (int c = 0; c < NCH; ++c)
                s += pflat[(size_t)(b * NCH + c) * 256 + t];
            out_flat[b * 256 + t] = s;
        } else {
            int f = t - 128;
            float m = -INFINITY;
            for (int c = 0; c < NCH; ++c)
                m = fmaxf(m, pflat[(size_t)(b * NCH + c) * 256 + 128 + f]);
            out_flat[b * 256 + 128 + f] = m;
        }
    } else {
        int e = (blk - BBG) * 256 + t;
        if (e >= EE) return;
        int s  = ei[e];
        int d  = ei[EE + e];
        int ns = nmap[s];
        int nd = nmap[d];
        bool keep = (ns >= 0) && (nd >= 0);
        out_edge[e]      = keep ? (float)ns : -1.0f;
        out_edge[EE + e] = keep ? (float)nd : -1.0f;
    }
}

extern "C" void kernel_launch(void* const* d_in, const int* in_sizes, int n_in,
                              void* d_out, int out_size, void* d_ws, size_t ws_size,
                              hipStream_t stream) {
    const float* x    = (const float*)d_in[0];
    const int*   ei   = (const int*)d_in[1];
    const float* Wl   = (const float*)d_in[3];
    const float* bl   = (const float*)d_in[4];
    const float* Wr   = (const float*)d_in[5];
    const float* gam  = (const float*)d_in[6];
    const float* bet  = (const float*)d_in[7];
    const float* attn = (const float*)d_in[8];

    // workspace layout
    float*    mean  = (float*)d_ws;                    // NN*FF
    float*    h     = mean + (size_t)NN * FF;          // NN*FF
    float*    score = h + (size_t)NN * FF;             // NN    (aliased: deg)
    int*      nmap  = (int*)(score + NN);              // NN    (aliased: spart)
    int*      plist = nmap + NN;                       // BBG*KKEEP
    float*    stats = (float*)(plist + BBG * KKEEP);   // 256
    ushort_t* Whi   = (ushort_t*)(stats + 256);        // 32768
    ushort_t* Wlo   = Whi + 32768;                     // 32768
    int*      starts = (int*)(Wlo + 32768);            // NN+1
    int*      cursor = starts + NN + 1;                // NN
    int*      ssrc   = cursor + NN;                    // EE
    int*      bsum   = ssrc + EE;                      // 256
    float*    pstats = (float*)(bsum + 256);           // 256*256
    float*    pflat  = pstats + 256 * 256;             // 1280*256

    int* deg   = (int*)score;   // dead after k_scan23; score written later
    int* spart = (int*)nmap;    // dead after k_scan23; nmap fully written by k_topk

    // output layout (all float32)
    float* out       = (float*)d_out;
    float* out_hp    = out;                                // 52480*128
    float* out_flat  = out_hp + (size_t)BBG * KKEEP * FF;  // 64*256
    float* out_edge  = out_flat + BBG * 256;               // 2*EE
    float* out_batch = out_edge + 2 * EE;                  // 52480

    hipMemsetAsync(deg, 0, (size_t)NN * sizeof(int), stream);

    k_init<<<128 + EE / 256, 256, 0, stream>>>(Wl, Wr, Whi, Wlo, ei, deg);
    k_scan1<<<256, 256, 0, stream>>>(deg, spart, bsum);
    k_scan23<<<256, 256, 0, stream>>>(deg, spart, bsum, starts, cursor);
    k_scatter<<<EE / 256, 256, 0, stream>>>(ei, cursor, ssrc);
    k_sortnb<<<NN / 256, 256, 0, stream>>>(starts, ssrc);
    k_gather<<<NN / 4, 256, 0, stream>>>(x, ssrc, starts, mean);
    k_gemm_mfma<<<NN / 256, 512, 0, stream>>>(mean, x, Whi, Wlo, bl, h, pstats);
    k_red<<<1, 256, 0, stream>>>(pstats, stats);
    k_score<<<NN / 8, 256, 0, stream>>>(h, stats, gam, bet, attn, score);
    k_topk<<<BBG, 1024, 0, stream>>>(score, nmap, plist, out_batch);
    k_hp2<<<BBG * NCH, 256, 0, stream>>>(h, score, plist, stats, gam, bet, out_hp, pflat);
    k_tail<<<BBG + EE / 256, 256, 0, stream>>>(pflat, out_flat, ei, nmap, out_edge);
}

// Round 18
// 207.612 us; speedup vs baseline: 1.2249x; 1.0039x over previous
//
#include <hip/hip_runtime.h>
#include <hip/hip_bf16.h>
#include <math.h>

#define NN    65536
#define EE    524288
#define BBG   64
#define PERG  1024
#define KKEEP 820
#define FF    128
#define EPSBN 1e-5f
#define CHUNK 41
#define NCH   20

typedef __attribute__((ext_vector_type(8))) short bf16x8;
typedef __attribute__((ext_vector_type(4))) float f32x4;
typedef unsigned short ushort_t;
typedef unsigned int uint_t;

// ---------------- fused: W split (blocks 0..127) + degree histogram (rest) ----------------
__global__ __launch_bounds__(256) void k_init(const float* __restrict__ Wl,
                                              const float* __restrict__ Wr,
                                              ushort_t* __restrict__ Whi,
                                              ushort_t* __restrict__ Wlo,
                                              const int* __restrict__ ei,
                                              int* __restrict__ deg) {
    int blk = blockIdx.x;
    int tid = threadIdx.x;
    if (blk < 128) {
        int i = blk * 256 + tid;              // 0..32767
        int o = i >> 8, k = i & 255;
        float v = (k < 128) ? Wl[o * FF + k] : Wr[o * FF + k - 128];
        uint_t u = __float_as_uint(v);
        float hif = __uint_as_float(u & 0xffff0000u);
        float lof = v - hif;
        Whi[i] = (ushort_t)(u >> 16);
        Wlo[i] = (ushort_t)(__float_as_uint(lof) >> 16);
    } else {
        int e = (blk - 128) * 256 + tid;
        if (e < EE) atomicAdd(&deg[ei[EE + e]], 1);
    }
}

// ---------------- scan stage 1: per-block inclusive scan + block sums ----------------
__global__ __launch_bounds__(256) void k_scan1(const int* __restrict__ deg,
                                               int* __restrict__ spart,
                                               int* __restrict__ bsum) {
    int t = threadIdx.x;
    int i = blockIdx.x * 256 + t;
    __shared__ int sh[256];
    int v = deg[i];
    sh[t] = v;
    __syncthreads();
    for (int o = 1; o < 256; o <<= 1) {
        int u = (t >= o) ? sh[t - o] : 0;
        __syncthreads();
        sh[t] += u;
        __syncthreads();
    }
    spart[i] = sh[t];
    if (t == 255) bsum[blockIdx.x] = sh[255];
}

// ---------------- scan stages 2+3 fused: every block scans bsum, emits starts ----------------
__global__ __launch_bounds__(256) void k_scan23(const int* __restrict__ deg,
                                                const int* __restrict__ spart,
                                                const int* __restrict__ bsum,
                                                int* __restrict__ starts,
                                                int* __restrict__ cursor) {
    int t = threadIdx.x;
    __shared__ int sh[256];
    __shared__ int orig[256];
    int v = bsum[t];
    orig[t] = v;
    sh[t] = v;
    __syncthreads();
    for (int o = 1; o < 256; o <<= 1) {
        int u = (t >= o) ? sh[t - o] : 0;
        __syncthreads();
        sh[t] += u;
        __syncthreads();
    }
    int bo = sh[blockIdx.x] - orig[blockIdx.x];   // exclusive block offset
    int i  = blockIdx.x * 256 + t;
    int st = spart[i] - deg[i] + bo;
    starts[i] = st;
    cursor[i] = st;
    if (i == 0) starts[NN] = EE;
}

// ---------------- scatter edges into CSR ----------------
__global__ __launch_bounds__(256) void k_scatter(const int* __restrict__ ei,
                                                 int* __restrict__ cursor,
                                                 int* __restrict__ ssrc) {
    int e = blockIdx.x * 256 + threadIdx.x;
    if (e >= EE) return;
    int s = ei[e];
    int d = ei[EE + e];
    int pos = atomicAdd(&cursor[d], 1);
    ssrc[pos] = s;
}

// ---------------- per-node neighbor-list sort: make ssrc deterministic ----------------
__global__ __launch_bounds__(256) void k_sortnb(const int* __restrict__ starts,
                                                int* __restrict__ ssrc) {
    int n = blockIdx.x * 256 + threadIdx.x;
    if (n >= NN) return;
    int d0 = starts[n], d1 = starts[n + 1];
    for (int i = d0 + 1; i < d1; ++i) {
        int key = ssrc[i];
        int j = i - 1;
        while (j >= d0 && ssrc[j] > key) {
            ssrc[j + 1] = ssrc[j];
            --j;
        }
        ssrc[j + 1] = key;
    }
}

// ---------------- per-node mean gather: one wave/node, float4, 8 loads in flight ----
__global__ __launch_bounds__(256) void k_gather(const float* __restrict__ x,
                                                const int* __restrict__ ssrc,
                                                const int* __restrict__ starts,
                                                float* __restrict__ mean) {
    int n    = blockIdx.x * 4 + (threadIdx.x >> 6);
    int lane = threadIdx.x & 63;
    int half = lane >> 5;            // neighbor parity
    int l32  = lane & 31;            // feature quad: f = l32*4
    int d0 = starts[n], d1 = starts[n + 1];

    f32x4 a0 = (f32x4){0.f, 0.f, 0.f, 0.f};
    f32x4 a1 = (f32x4){0.f, 0.f, 0.f, 0.f};
    f32x4 a2 = (f32x4){0.f, 0.f, 0.f, 0.f};
    f32x4 a3 = (f32x4){0.f, 0.f, 0.f, 0.f};
    int e = d0 + half;
    for (; e + 6 < d1; e += 8) {
        int s0 = ssrc[e];
        int s1 = ssrc[e + 2];
        int s2 = ssrc[e + 4];
        int s3 = ssrc[e + 6];
        a0 += *(const f32x4*)(x + (size_t)s0 * FF + l32 * 4);
        a1 += *(const f32x4*)(x + (size_t)s1 * FF + l32 * 4);
        a2 += *(const f32x4*)(x + (size_t)s2 * FF + l32 * 4);
        a3 += *(const f32x4*)(x + (size_t)s3 * FF + l32 * 4);
    }
    if (e < d1) {
        a0 += *(const f32x4*)(x + (size_t)ssrc[e] * FF + l32 * 4);
        e += 2;
    }
    if (e < d1) {
        a1 += *(const f32x4*)(x + (size_t)ssrc[e] * FF + l32 * 4);
        e += 2;
    }
    if (e < d1) {
        a2 += *(const f32x4*)(x + (size_t)ssrc[e] * FF + l32 * 4);
    }
    f32x4 acc = (a0 + a1) + (a2 + a3);
    f32x4 oth;
#pragma unroll
    for (int j = 0; j < 4; ++j) oth[j] = __shfl_xor(acc[j], 32);
    acc += oth;
    if (half == 0) {
        float inv = 1.0f / fmaxf((float)(d1 - d0), 1.0f);
        acc *= inv;
        *(f32x4*)(mean + (size_t)n * FF + l32 * 4) = acc;
    }
}

// ---------------- h = [mean||x] @ [Wl||Wr]^T + bl  via MFMA, B fully in LDS ----
__global__ __launch_bounds__(512, 1) void k_gemm_mfma(const float* __restrict__ mean,
                                                      const float* __restrict__ x,
                                                      const ushort_t* __restrict__ Whi,
                                                      const ushort_t* __restrict__ Wlo,
                                                      const float* __restrict__ blv,
                                                      float* __restrict__ h,
                                                      float* __restrict__ pstats) {
    __shared__ __align__(16) ushort_t Bst[65536];   // 128 KB
    __shared__ float ls1[8][128], ls2[8][128];      // 8 KB
    const int tid = threadIdx.x;

#pragma unroll
    for (int i = 0; i < 16; ++i) {
        int q = tid + i * 512;          // cell id = c*256 + idx
        int c = q >> 8, idx = q & 255;
        const ushort_t* src = (idx < 128) ? (Whi + idx * 256 + c * 8)
                                          : (Wlo + (idx - 128) * 256 + c * 8);
        *(bf16x8*)&Bst[q * 8] = *(const bf16x8*)src;
    }
    __syncthreads();

    const int w    = tid >> 6;
    const int lane = tid & 63;
    const int kof  = (lane >> 4) * 8;
    const int bcol = lane & 15;
    const int r0   = blockIdx.x * 256 + w * 32;

    const float* __restrict__ pm0 = mean + (size_t)(r0 + (lane & 15)) * FF + kof;
    const float* __restrict__ px0 = x    + (size_t)(r0 + (lane & 15)) * FF + kof;
    const float* __restrict__ pm1 = pm0 + 16 * FF;
    const float* __restrict__ px1 = px0 + 16 * FF;

    f32x4 acc[2][8];
#pragma unroll
    for (int rt = 0; rt < 2; ++rt)
#pragma unroll
        for (int n = 0; n < 8; ++n) acc[rt][n] = (f32x4){0.f, 0.f, 0.f, 0.f};

    f32x4 a0c[2], a1c[2];
    a0c[0] = *(const f32x4*)pm0;
    a1c[0] = *(const f32x4*)(pm0 + 4);
    a0c[1] = *(const f32x4*)pm1;
    a1c[1] = *(const f32x4*)(pm1 + 4);

#pragma unroll
    for (int ks = 0; ks < 8; ++ks) {
        const int k0 = ks * 32;
        f32x4 a0n[2], a1n[2];
        if (ks < 7) {
            const int kn = k0 + 32;
            const float* pn0 = (kn < 128) ? (pm0 + kn) : (px0 + (kn - 128));
            const float* pn1 = (kn < 128) ? (pm1 + kn) : (px1 + (kn - 128));
            a0n[0] = *(const f32x4*)pn0;
            a1n[0] = *(const f32x4*)(pn0 + 4);
            a0n[1] = *(const f32x4*)pn1;
            a1n[1] = *(const f32x4*)(pn1 + 4);
        }
        bf16x8 ah[2], al[2];
#pragma unroll
        for (int rt = 0; rt < 2; ++rt)
#pragma unroll
            for (int e = 0; e < 8; ++e) {
                float v = (e < 4) ? a0c[rt][e] : a1c[rt][e - 4];
                uint_t u = __float_as_uint(v);
                float hif = __uint_as_float(u & 0xffff0000u);
                float lof = v - hif;
                ah[rt][e] = (short)(u >> 16);
                al[rt][e] = (short)(__float_as_uint(lof) >> 16);
            }
        const int cbase = (ks * 4 + (lane >> 4)) * 256;
#pragma unroll
        for (int n = 0; n < 8; ++n) {
            int oo = n * 16 + bcol;
            bf16x8 bh = *(const bf16x8*)&Bst[(cbase + oo) * 8];
            bf16x8 bl = *(const bf16x8*)&Bst[(cbase + 128 + oo) * 8];
#pragma unroll
            for (int rt = 0; rt < 2; ++rt) {
                acc[rt][n] = __builtin_amdgcn_mfma_f32_16x16x32_bf16(ah[rt], bh, acc[rt][n], 0, 0, 0);
                acc[rt][n] = __builtin_amdgcn_mfma_f32_16x16x32_bf16(ah[rt], bl, acc[rt][n], 0, 0, 0);
                acc[rt][n] = __builtin_amdgcn_mfma_f32_16x16x32_bf16(al[rt], bh, acc[rt][n], 0, 0, 0);
            }
        }
        a0c[0] = a0n[0]; a1c[0] = a1n[0];
        a0c[1] = a0n[1]; a1c[1] = a1n[1];
    }

#pragma unroll
    for (int n = 0; n < 8; ++n) {
        int col = n * 16 + bcol;
        float b = blv[col];
        float p1 = 0.f, p2 = 0.f;
#pragma unroll
        for (int rt = 0; rt < 2; ++rt) {
            int orow = r0 + rt * 16 + (lane >> 4) * 4;
#pragma unroll
            for (int j = 0; j < 4; ++j) {
                float v = acc[rt][n][j] + b;
                h[(size_t)(orow + j) * FF + col] = v;
                p1 += v;
                p2 += v * v;
            }
        }
        p1 += __shfl_xor(p1, 16); p1 += __shfl_xor(p1, 32);
        p2 += __shfl_xor(p2, 16); p2 += __shfl_xor(p2, 32);
        if (lane < 16) { ls1[w][col] = p1; ls2[w][col] = p2; }
    }
    __syncthreads();
    if (tid < 128) {
        float a = 0.f, b2 = 0.f;
#pragma unroll
        for (int ww = 0; ww < 8; ++ww) {
            a  += ls1[ww][tid];
            b2 += ls2[ww][tid];
        }
        pstats[(size_t)blockIdx.x * 256 + tid]       = a;
        pstats[(size_t)blockIdx.x * 256 + 128 + tid] = b2;
    }
}

// ---------------- stats reduction: one block, bit-identical nested 16x16 order ----------------
__global__ __launch_bounds__(256) void k_red(const float* __restrict__ pstats,
                                             float* __restrict__ stats) {
    int t = threadIdx.x;
    float s = 0.f;
    for (int r = 0; r < 16; ++r) {
        float g = 0.f;
        for (int i = 0; i < 16; ++i)
            g += pstats[(size_t)(r * 16 + i) * 256 + t];
        s += g;
    }
    stats[t] = s;
}

// ---------------- score (BN params inline) ----------------
__global__ __launch_bounds__(256) void k_score(const float* __restrict__ h,
                                               const float* __restrict__ stats,
                                               const float* __restrict__ gamma,
                                               const float* __restrict__ beta,
                                               const float* __restrict__ attn,
                                               float* __restrict__ score) {
    int tid = threadIdx.x;
    int l32 = tid & 31;
    int n   = blockIdx.x * 8 + (tid >> 5);
    int f0  = l32 * 4;
    float4 su = *(const float4*)&stats[f0];
    float4 sq = *(const float4*)&stats[128 + f0];
    float4 g4 = *(const float4*)&gamma[f0];
    float4 b4 = *(const float4*)&beta[f0];
    float4 a4 = *(const float4*)&attn[f0];
    float an = a4.x * a4.x + a4.y * a4.y + a4.z * a4.z + a4.w * a4.w;
#pragma unroll
    for (int off = 16; off > 0; off >>= 1) an += __shfl_xor(an, off);
    float inva = 1.0f / sqrtf(an);
    float invN = 1.0f / (float)NN;
    float m0 = su.x * invN, m1 = su.y * invN, m2 = su.z * invN, m3 = su.w * invN;
    float sc0 = g4.x / sqrtf(sq.x * invN - m0 * m0 + EPSBN);
    float sc1 = g4.y / sqrtf(sq.y * invN - m1 * m1 + EPSBN);
    float sc2 = g4.z / sqrtf(sq.z * invN - m2 * m2 + EPSBN);
    float sc3 = g4.w / sqrtf(sq.w * invN - m3 * m3 + EPSBN);
    float4 hv = *(const float4*)&h[(size_t)n * FF + f0];
    float v0 = fmaxf((hv.x - m0) * sc0 + b4.x, 0.f);
    float v1 = fmaxf((hv.y - m1) * sc1 + b4.y, 0.f);
    float v2 = fmaxf((hv.z - m2) * sc2 + b4.z, 0.f);
    float v3 = fmaxf((hv.w - m3) * sc3 + b4.w, 0.f);
    float s = (v0 * a4.x + v1 * a4.y + v2 * a4.z + v3 * a4.w) * inva;
#pragma unroll
    for (int off = 16; off > 0; off >>= 1) s += __shfl_xor(s, off);
    if (l32 == 0) score[n] = s;
}

// ---------------- per-graph bitonic sort: register/shfl j<64, LDS j>=64 ----------------
// Writes ALL nmap entries (kept -> nid, dropped -> -1): no nmap memset needed.
__global__ __launch_bounds__(1024) void k_topk(const float* __restrict__ score,
                                               int* __restrict__ nmap,
                                               int* __restrict__ plist,
                                               float* __restrict__ out_batch) {
    __shared__ unsigned long long sh[PERG];
    int b = blockIdx.x;
    int t = threadIdx.x;
    float s = score[b * PERG + t];
    unsigned u = __float_as_uint(s);
    u = (u & 0x80000000u) ? ~u : (u | 0x80000000u);
    unsigned long long key = ((unsigned long long)u << 10) | (unsigned long long)(1023 - t);

    for (int k = 2; k <= PERG; k <<= 1) {
        bool asc = (t & k) != 0;
        for (int j = k >> 1; j > 0; j >>= 1) {
            bool upper = (t & j) != 0;
            unsigned long long other;
            if (j >= 64) {
                __syncthreads();
                sh[t] = key;
                __syncthreads();
                other = sh[t ^ j];
            } else {
                other = __shfl_xor(key, j, 64);
            }
            bool takeMax = (asc == upper);
            key = takeMax ? (key > other ? key : other)
                          : (key < other ? key : other);
        }
    }

    int idx = 1023 - (int)(key & 1023ull);
    int g   = b * PERG + idx;
    if (t < KKEEP) {
        int nid = b * KKEEP + t;
        plist[nid]     = g;
        nmap[g]        = nid;
        out_batch[nid] = (float)b;
    } else {
        nmap[g] = -1;
    }
}

// ---------------- hp = BNrelu(h[perm]) * tanh(score[perm]) + fused pool partials ----
__global__ __launch_bounds__(256) void k_hp2(const float* __restrict__ h,
                                             const float* __restrict__ score,
                                             const int* __restrict__ plist,
                                             const float* __restrict__ stats,
                                             const float* __restrict__ gamma,
                                             const float* __restrict__ beta,
                                             float* __restrict__ out_hp,
                                             float* __restrict__ pflat) {
    int b   = blockIdx.x;             // 0..1279
    int g   = b / NCH, c = b % NCH;
    int tid = threadIdx.x;
    int f   = tid & 127, half = tid >> 7;
    int r0  = g * KKEEP + c * CHUNK;

    __shared__ float tts[CHUNK];
    __shared__ int   gl[CHUNK];
    if (tid < CHUNK) {
        int gg = plist[r0 + tid];
        gl[tid]  = gg;
        tts[tid] = tanhf(score[gg]);
    }
    __syncthreads();

    float invN = 1.0f / (float)NN;
    float m  = stats[f] * invN;
    float sc = gamma[f] / sqrtf(stats[128 + f] * invN - m * m + EPSBN);
    float bb = beta[f];
    float s = 0.f, mx = -INFINITY;
    for (int i = half; i < CHUNK; i += 2) {
        int gg = gl[i];
        float v = fmaxf((h[(size_t)gg * FF + f] - m) * sc + bb, 0.f) * tts[i];
        out_hp[(size_t)(r0 + i) * FF + f] = v;
        s += v;
        mx = fmaxf(mx, v);
    }
    __shared__ float ls[256], lm[256];
    ls[tid] = s;
    lm[tid] = mx;
    __syncthreads();
    if (half == 0) {
        pflat[(size_t)b * 256 + f]       = ls[f] + ls[128 + f];
        pflat[(size_t)b * 256 + 128 + f] = fmaxf(lm[f], lm[128 + f]);
    }
}

// ---------------- fused tail: per-graph combine (blocks 0..63) + edge reindex ----------------
__global__ __launch_bounds__(256) void k_tail(const float* __restrict__ pflat,
                                              float* __restrict__ out_flat,
                                              const int* __restrict__ ei,
                                              const int* __restrict__ nmap,
                                              float* __restrict__ out_edge) {
    int blk = blockIdx.x;
    int t   = threadIdx.x;
    if (blk < BBG) {
        int b = blk;
        if (t < 128) {
            float s = 0.f;
            for (int c = 0; c < NCH; ++c)
                s += pflat[(size_t)(b * NCH + c) * 256 + t];
            out_flat[b * 256 + t] = s;
        } else {
            int f = t - 128;
            float m = -INFINITY;
            for (int c = 0; c < NCH; ++c)
                m = fmaxf(m, pflat[(size_t)(b * NCH + c) * 256 + 128 + f]);
            out_flat[b * 256 + 128 + f] = m;
        }
    } else {
        int e = (blk - BBG) * 256 + t;
        if (e >= EE) return;
        int s  = ei[e];
        int d  = ei[EE + e];
        int ns = nmap[s];
        int nd = nmap[d];
        bool keep = (ns >= 0) && (nd >= 0);
        out_edge[e]      = keep ? (float)ns : -1.0f;
        out_edge[EE + e] = keep ? (float)nd : -1.0f;
    }
}

extern "C" void kernel_launch(void* const* d_in, const int* in_sizes, int n_in,
                              void* d_out, int out_size, void* d_ws, size_t ws_size,
                              hipStream_t stream) {
    const float* x    = (const float*)d_in[0];
    const int*   ei   = (const int*)d_in[1];
    const float* Wl   = (const float*)d_in[3];
    const float* bl   = (const float*)d_in[4];
    const float* Wr   = (const float*)d_in[5];
    const float* gam  = (const float*)d_in[6];
    const float* bet  = (const float*)d_in[7];
    const float* attn = (const float*)d_in[8];

    // workspace layout
    float*    mean  = (float*)d_ws;                    // NN*FF
    float*    h     = mean + (size_t)NN * FF;          // NN*FF
    float*    score = h + (size_t)NN * FF;             // NN    (aliased: deg)
    int*      nmap  = (int*)(score + NN);              // NN    (aliased: spart)
    int*      plist = nmap + NN;                       // BBG*KKEEP
    float*    stats = (float*)(plist + BBG * KKEEP);   // 256
    ushort_t* Whi   = (ushort_t*)(stats + 256);        // 32768
    ushort_t* Wlo   = Whi + 32768;                     // 32768
    int*      starts = (int*)(Wlo + 32768);            // NN+1
    int*      cursor = starts + NN + 1;                // NN
    int*      ssrc   = cursor + NN;                    // EE
    int*      bsum   = ssrc + EE;                      // 256
    float*    pstats = (float*)(bsum + 256);           // 256*256
    float*    pflat  = pstats + 256 * 256;             // 1280*256

    int* deg   = (int*)score;   // dead after k_scan23; score written later
    int* spart = (int*)nmap;    // dead after k_scan23; nmap fully written by k_topk

    // output layout (all float32)
    float* out       = (float*)d_out;
    float* out_hp    = out;                                // 52480*128
    float* out_flat  = out_hp + (size_t)BBG * KKEEP * FF;  // 64*256
    float* out_edge  = out_flat + BBG * 256;               // 2*EE
    float* out_batch = out_edge + 2 * EE;                  // 52480

    hipMemsetAsync(deg, 0, (size_t)NN * sizeof(int), stream);

    k_init<<<128 + EE / 256, 256, 0, stream>>>(Wl, Wr, Whi, Wlo, ei, deg);
    k_scan1<<<256, 256, 0, stream>>>(deg, spart, bsum);
    k_scan23<<<256, 256, 0, stream>>>(deg, spart, bsum, starts, cursor);
    k_scatter<<<EE / 256, 256, 0, stream>>>(ei, cursor, ssrc);
    k_sortnb<<<NN / 256, 256, 0, stream>>>(starts, ssrc);
    k_gather<<<NN / 4, 256, 0, stream>>>(x, ssrc, starts, mean);
    k_gemm_mfma<<<NN / 256, 512, 0, stream>>>(mean, x, Whi, Wlo, bl, h, pstats);
    k_red<<<1, 256, 0, stream>>>(pstats, stats);
    k_score<<<NN / 8, 256, 0, stream>>>(h, stats, gam, bet, attn, score);
    k_topk<<<BBG, 1024, 0, stream>>>(score, nmap, plist, out_batch);
    k_hp2<<<BBG * NCH, 256, 0, stream>>>(h, score, plist, stats, gam, bet, out_hp, pflat);
    k_tail<<<BBG + EE / 256, 256, 0, stream>>>(pflat, out_flat, ei, nmap, out_edge);
}